// Round 6
// baseline (2435.236 us; speedup 1.0000x reference)
//
#include <hip/hip_runtime.h>
#include <hip/hip_fp16.h>
#include <math.h>

// Single persistent cooperative kernel for MI355X (gfx950), 256 blocks x 512.
// Each CU owns a 16-dim slice: its 32-row bf16 trig table T1s lives in LDS for
// the WHOLE run (no global T1 at all). Per iteration:
//   [wexp]  each CU reduces its 32-entry (b,k)-chunk of W = exp2(c2*sum_ds P)
//           (unnormalized softmax: atan2 direction is scale-invariant)
//   gbar
//   [step2] load full W (32KB bcast) -> est-GEMM (re/im, DPP wave reduce) ->
//           normalize est in LDS (cos=re/|z|,sin=im/|z|; no atan2) ->
//           sims partials for next iter -> fp16 P store
//   gbar
// Exchange is atomic-free: P[256 slices][8][1024] fp16 (4 MB) + W (32 KB).
// ~16 MB global traffic per iteration, 2 grid barriers, 1 kernel launch.

#define NBLK   256
#define NTHR   512
#define KCODES 1024
#define DIMS   4096
#define BATCH  8
#define NSLICE 256

// ws float offsets
#define P_OFF   0
#define P_SZF   (NSLICE * BATCH * KCODES / 2)   // fp16 P occupies 1,048,576 f32 slots
#define W_OFF   P_SZF                            // f32 [8][1024]
#define W_SZ    (BATCH * KCODES)
#define CNT_OFF (W_OFF + W_SZ)                   // barrier counter

#define C2 (0.00244140625f * 1.4426950408889634f)   // (10/4096)*log2(e)

// ---- bf16 helpers ----
__device__ __forceinline__ ushort f2bf(float x) {
  unsigned u = __float_as_uint(x);
  return (ushort)((u + 0x7FFFu + ((u >> 16) & 1u)) >> 16);   // RNE
}
__device__ __forceinline__ float bf2f(ushort u) {
  return __uint_as_float(((unsigned)u) << 16);
}

// ---- DPP wave64 sum: result valid in lane 63 ----
template <int CTRL>
__device__ __forceinline__ float dpp_add(float x) {
  int v = __builtin_amdgcn_update_dpp(0, __float_as_int(x), CTRL, 0xF, 0xF, false);
  return x + __int_as_float(v);
}
__device__ __forceinline__ float wave_sum64(float x) {
  x = dpp_add<0x111>(x);   // row_shr:1
  x = dpp_add<0x112>(x);   // row_shr:2
  x = dpp_add<0x114>(x);   // row_shr:4
  x = dpp_add<0x118>(x);   // row_shr:8
  x = dpp_add<0x142>(x);   // row_bcast:15
  x = dpp_add<0x143>(x);   // row_bcast:31
  return x;                // lane 63 = sum of all 64 lanes
}

__device__ __forceinline__ void grid_barrier(unsigned* cnt, unsigned target) {
  __syncthreads();
  if (threadIdx.x == 0) {
    __threadfence();  // agent-scope release: publish this XCD's writes
    __hip_atomic_fetch_add(cnt, 1u, __ATOMIC_RELEASE, __HIP_MEMORY_SCOPE_AGENT);
    while (__hip_atomic_load(cnt, __ATOMIC_ACQUIRE, __HIP_MEMORY_SCOPE_AGENT) < target) {
      __builtin_amdgcn_s_sleep(2);
    }
  }
  __syncthreads();
}

__global__ __launch_bounds__(NTHR) void resonator_persist(
    const float* __restrict__ sup,    // (8,4096) superposed angles
    const float* __restrict__ cb,     // (1024,4096) codebook angles
    const int*  __restrict__ nit_p,   // num_iterations
    float* __restrict__ out,          // (8,1024)
    float* ws)
{
  // LDS: 64 KB T1 slice + 32 KB W/scratch + 1 KB est = 97.25 KB
  __shared__ ushort T1s[32][KCODES];        // [row=2*dl+cs][k], bf16
  __shared__ float  smem[BATCH * KCODES];   // W for est-GEMM; sims-combine scratch
  __shared__ float  est_l[32 * BATCH];      // est rows; also wexp wave-partials

  __half*   P   = (__half*)(ws + P_OFF);
  float*    Wg  = ws + W_OFF;
  unsigned* cnt = (unsigned*)(ws + CNT_OFF);

  const int t    = threadIdx.x;
  const int bid  = blockIdx.x;
  const int lane = t & 63;
  const int wv   = t >> 6;
  const int ds   = bid;              // slice id = 16 dims
  const int d0   = ds * 16;
  const int NI   = *nit_p;

  // ---- sims: P[ds][b][k] = sum_rows est_l[row][b]*T1s[row][k] (row-split) --
  auto sims_to_P = [&]() {
    const int half = t >> 8, tk = t & 255, k4 = tk * 4;
    float4 a[BATCH];
    #pragma unroll
    for (int b = 0; b < BATCH; ++b) a[b] = make_float4(0.f, 0.f, 0.f, 0.f);
    const int rb = half * 16;
    #pragma unroll
    for (int r = 0; r < 16; ++r) {
      const int row = rb + r;
      const ushort4 tu = *(const ushort4*)&T1s[row][k4];
      const float4 tv = make_float4(bf2f(tu.x), bf2f(tu.y), bf2f(tu.z), bf2f(tu.w));
      const float4 e0 = *(const float4*)&est_l[row * BATCH + 0];
      const float4 e1 = *(const float4*)&est_l[row * BATCH + 4];
      const float ev[8] = {e0.x, e0.y, e0.z, e0.w, e1.x, e1.y, e1.z, e1.w};
      #pragma unroll
      for (int b = 0; b < BATCH; ++b) {
        a[b].x = fmaf(ev[b], tv.x, a[b].x);
        a[b].y = fmaf(ev[b], tv.y, a[b].y);
        a[b].z = fmaf(ev[b], tv.z, a[b].z);
        a[b].w = fmaf(ev[b], tv.w, a[b].w);
      }
    }
    if (half == 1) {
      #pragma unroll
      for (int b = 0; b < BATCH; ++b)
        *(float4*)&smem[(b * 256 + tk) * 4] = a[b];     // lane-stride 16B: no conflicts
    }
    __syncthreads();
    if (half == 0) {
      #pragma unroll
      for (int b = 0; b < BATCH; ++b) {
        const float4 o = *(const float4*)&smem[(b * 256 + tk) * 4];
        const float x0 = a[b].x + o.x, x1 = a[b].y + o.y;
        const float x2 = a[b].z + o.z, x3 = a[b].w + o.w;
        __half* pp = P + (size_t)ds * (BATCH * KCODES) + b * KCODES + k4;
        *(__half2*)(pp + 0) = __floats2half2_rn(x0, x1);
        *(__half2*)(pp + 2) = __floats2half2_rn(x2, x3);
      }
    }
  };

  // ---- column-reduce P over slices for this CU's 32-entry (b,k) chunk ------
  auto col_reduce32 = [&](float* dst, bool do_exp) {
    const int b2 = bid >> 5;
    const int k0 = (bid & 31) * 32;
    if (t < 256) {
      float4 raw[4];
      const float4* p4 =
          (const float4*)(P + (size_t)t * (BATCH * KCODES) + b2 * KCODES + k0);
      raw[0] = p4[0]; raw[1] = p4[1]; raw[2] = p4[2]; raw[3] = p4[3];
      const __half2* h2 = (const __half2*)raw;
      #pragma unroll
      for (int kk = 0; kk < 16; ++kk) {
        const float2 f2 = __half22float2(h2[kk]);
        const float s0 = wave_sum64(f2.x);
        const float s1 = wave_sum64(f2.y);
        if (lane == 63) {
          est_l[wv * 32 + 2 * kk + 0] = s0;
          est_l[wv * 32 + 2 * kk + 1] = s1;
        }
      }
    }
    __syncthreads();
    if (t < 32) {
      const float s = est_l[t] + est_l[32 + t] + est_l[64 + t] + est_l[96 + t];
      dst[b2 * KCODES + k0 + t] = do_exp ? exp2f(s * C2) : s * (1.0f / (float)DIMS);
    }
    __syncthreads();
  };

  // ---- step2: W -> est-GEMM -> normalize -> next sims ----------------------
  auto step2 = [&]() {
    #pragma unroll
    for (int j = 0; j < 4; ++j) {                    // load full W into LDS
      const int idx = (j * NTHR + t) * 4;
      *(float4*)&smem[idx] = *(const float4*)&Wg[idx];
    }
    __syncthreads();

    const int rw = wv * 4;                           // wave's 4 T1 rows
    float acc[4][BATCH];
    #pragma unroll
    for (int r = 0; r < 4; ++r)
      #pragma unroll
      for (int b = 0; b < BATCH; ++b) acc[r][b] = 0.f;

    #pragma unroll
    for (int c = 0; c < 4; ++c) {
      const int kk = c * 256 + lane * 4;
      float4 wr[BATCH];
      #pragma unroll
      for (int b = 0; b < BATCH; ++b)
        wr[b] = *(const float4*)&smem[b * KCODES + kk];
      #pragma unroll
      for (int r = 0; r < 4; ++r) {
        const ushort4 tu = *(const ushort4*)&T1s[rw + r][kk];
        const float4 tv = make_float4(bf2f(tu.x), bf2f(tu.y), bf2f(tu.z), bf2f(tu.w));
        #pragma unroll
        for (int b = 0; b < BATCH; ++b) {
          acc[r][b] = fmaf(wr[b].x, tv.x, acc[r][b]);
          acc[r][b] = fmaf(wr[b].y, tv.y, acc[r][b]);
          acc[r][b] = fmaf(wr[b].z, tv.z, acc[r][b]);
          acc[r][b] = fmaf(wr[b].w, tv.w, acc[r][b]);
        }
      }
    }
    #pragma unroll
    for (int r = 0; r < 4; ++r)
      #pragma unroll
      for (int b = 0; b < BATCH; ++b) {
        const float s = wave_sum64(acc[r][b]);
        if (lane == 63) est_l[(rw + r) * BATCH + b] = s;
      }
    __syncthreads();

    if (t < 128) {                                   // normalize est in LDS
      const int dl = t >> 3, b = t & 7;
      const float re = est_l[(2 * dl + 0) * BATCH + b];
      const float im = est_l[(2 * dl + 1) * BATCH + b];
      const float n2 = fmaf(re, re, im * im);
      float ec, es;
      if (n2 > 0.f) {
        const float inv = rsqrtf(n2);
        ec = re * inv; es = im * inv;
      } else { ec = 1.f; es = 0.f; }                 // atan2(0,0) = 0
      est_l[(2 * dl + 0) * BATCH + b] = ec;
      est_l[(2 * dl + 1) * BATCH + b] = es;
    }
    __syncthreads();
    sims_to_P();
  };

  // ================= prologue: T1 slice + est0 + P0 =========================
  for (int kq = t; kq < KCODES; kq += NTHR) {        // trig build (coalesced 64B)
    const float* crow = cb + (size_t)kq * DIMS + d0;
    const float4 a0 = *(const float4*)(crow + 0);
    const float4 a1 = *(const float4*)(crow + 4);
    const float4 a2 = *(const float4*)(crow + 8);
    const float4 a3 = *(const float4*)(crow + 12);
    const float av[16] = {a0.x, a0.y, a0.z, a0.w, a1.x, a1.y, a1.z, a1.w,
                          a2.x, a2.y, a2.z, a2.w, a3.x, a3.y, a3.z, a3.w};
    #pragma unroll
    for (int dl = 0; dl < 16; ++dl) {
      float s, c; sincosf(av[dl], &s, &c);
      T1s[2 * dl + 0][kq] = f2bf(c);
      T1s[2 * dl + 1][kq] = f2bf(s);
    }
  }
  if (t < 128) {
    const int b = t >> 4, dl = t & 15;
    float s, c; sincosf(sup[(size_t)b * DIMS + d0 + dl], &s, &c);
    est_l[(2 * dl + 0) * BATCH + b] = c;
    est_l[(2 * dl + 1) * BATCH + b] = s;
  }
  __syncthreads();
  sims_to_P();

  unsigned barnum = 0;
  grid_barrier(cnt, (++barnum) * NBLK);

  // ================= main loop =============================================
  for (int it = 0; it < NI; ++it) {
    col_reduce32(Wg, true);                          // W chunk
    grid_barrier(cnt, (++barnum) * NBLK);
    step2();                                         // est update + next P
    grid_barrier(cnt, (++barnum) * NBLK);
  }

  // ================= epilogue: out = (sum_ds P)/DIMS ========================
  col_reduce32(out, false);
}

extern "C" void kernel_launch(void* const* d_in, const int* in_sizes, int n_in,
                              void* d_out, int out_size, void* d_ws, size_t ws_size,
                              hipStream_t stream) {
  const float* sup = (const float*)d_in[0];
  const float* cbk = (const float*)d_in[1];
  const int*   nit = (const int*)d_in[2];
  float* outp = (float*)d_out;
  float* ws   = (float*)d_ws;

  // Reset ONLY the barrier counter each launch (P/W/out fully overwritten
  // in-kernel before any read). Graph-capture safe.
  hipMemsetAsync((char*)d_ws + (size_t)CNT_OFF * sizeof(float), 0, 64, stream);

  void* args[] = { (void*)&sup, (void*)&cbk, (void*)&nit, (void*)&outp, (void*)&ws };
  hipLaunchCooperativeKernel((const void*)resonator_persist,
                             dim3(NBLK), dim3(NTHR), args, 0, stream);
}

// Round 7
// 730.600 us; speedup vs baseline: 3.3332x; 3.3332x over previous
//
#include <hip/hip_runtime.h>
#include <hip/hip_fp16.h>
#include <math.h>

// Multi-kernel resonator decoder for MI355X (gfx950) — round 7.
// Structure: 2 kernels/iteration on a graph-replayed stream (kernel boundary
// = barrier; no fences, no atomics, no spins).
//   k_wexp  : chunked all-reduce of fp16 partials P[256][8][1024] -> W =
//             exp2(c2*S) (unnormalized softmax: atan2 direction is
//             scale-invariant, Z cancels). 256 blocks, thread-per-slice,
//             DPP wave reduce (r6-proven col_reduce32).
//   k_fused : per 16-dim slice (block bid, stable bid->XCD affinity keeps its
//             64 KB bf16 T1 slice L2-hot across all 50 iters): W.T1 est-GEMM
//             (8 waves x 4 rows, DPP reduce) -> normalize est in LDS
//             (cos=re/|z|, sin=im/|z|; no atan2) -> next-iter sims partials
//             -> fp16 P store. (r6-proven step2+sims_to_P, T1 from global.)
// T1[row=d*2+cs][k] bf16 (16 MB), k-contiguous: coalesced in both phases.

#define KCODES 1024
#define DIMS   4096
#define BATCH  8
#define NITER_MAX 50          // device-side guard handles *nit_p < NITER_MAX
#define NSLICE 256            // P slices (16 dims each)

// ws layout (float offsets), ~21 MB total
#define T1_SZF   (DIMS * 2 * KCODES / 2)       // bf16 T1: 4,194,304 f32 slots
#define EST_OFF  (T1_SZF)
#define EST_SZ   (DIMS * 2 * BATCH)            // est[row][b] f32 (one-time)
#define W_OFF    (EST_OFF + EST_SZ)
#define W_SZ     (BATCH * KCODES)
#define P_OFF    (W_OFF + W_SZ)                // fp16 partials [ds][b][k]

#define C2 (0.00244140625f * 1.4426950408889634f)   // (10/4096)*log2(e)

// ---- bf16 helpers ----
__device__ __forceinline__ ushort f2bf(float x) {
  unsigned u = __float_as_uint(x);
  return (ushort)((u + 0x7FFFu + ((u >> 16) & 1u)) >> 16);   // RNE
}
__device__ __forceinline__ float bf2f(ushort u) {
  return __uint_as_float(((unsigned)u) << 16);
}

// ---- DPP wave64 sum: result valid in lane 63 ----
template <int CTRL>
__device__ __forceinline__ float dpp_add(float x) {
  int v = __builtin_amdgcn_update_dpp(0, __float_as_int(x), CTRL, 0xF, 0xF, false);
  return x + __int_as_float(v);
}
__device__ __forceinline__ float wave_sum64(float x) {
  x = dpp_add<0x111>(x);   // row_shr:1
  x = dpp_add<0x112>(x);   // row_shr:2
  x = dpp_add<0x114>(x);   // row_shr:4
  x = dpp_add<0x118>(x);   // row_shr:8
  x = dpp_add<0x142>(x);   // row_bcast:15
  x = dpp_add<0x143>(x);   // row_bcast:31
  return x;                // lane 63 = sum of all 64 lanes
}

// ---- one-time: codebook angles -> bf16 T1[(d*2+cs)][k] via LDS transpose ----
__global__ __launch_bounds__(256) void k_trig(const float* __restrict__ cb,
                                              float* __restrict__ ws) {
  __shared__ float lc[64][65], ls[64][65];
  const int t  = threadIdx.x;
  const int bk = blockIdx.x & 15;        // 16 k-tiles
  const int bd = blockIdx.x >> 4;        // 64 d-tiles
  const int k0 = bk * 64, d0 = bd * 64;
  const int c = t & 63;
  #pragma unroll
  for (int i = 0; i < 16; ++i) {
    const int r = (t >> 6) + i * 4;
    float a = cb[(size_t)(k0 + r) * DIMS + d0 + c];
    float s, cc; sincosf(a, &s, &cc);
    lc[r][c] = cc; ls[r][c] = s;
  }
  __syncthreads();
  ushort* T1 = (ushort*)ws;
  #pragma unroll
  for (int j = 0; j < 16; ++j) {
    const int dd = (t >> 6) + j * 4;
    T1[(size_t)((d0 + dd) * 2 + 0) * KCODES + k0 + c] = f2bf(lc[c][dd]);
    T1[(size_t)((d0 + dd) * 2 + 1) * KCODES + k0 + c] = f2bf(ls[c][dd]);
  }
}

// ---- one-time: est init from superposed (f32, read only by k_sims0) ----
__global__ __launch_bounds__(256) void k_init(const float* __restrict__ sup,
                                              float* __restrict__ ws) {
  float* EST = ws + EST_OFF;
  const int i = blockIdx.x * 256 + threadIdx.x;   // 0..32767
  const int b = i >> 12, d = i & 4095;
  float s, c; sincosf(sup[(size_t)b * DIMS + d], &s, &c);
  EST[(d * 2 + 0) * BATCH + b] = c;
  EST[(d * 2 + 1) * BATCH + b] = s;
}

// ---- one-time: initial partial sims from EST ----
__global__ __launch_bounds__(256) void k_sims0(float* __restrict__ ws) {
  const ushort* T1  = (const ushort*)ws;
  const float*  EST = ws + EST_OFF;
  __half* P = (__half*)(ws + P_OFF);
  const int t  = threadIdx.x;
  const int ds = blockIdx.x;
  const int r0 = ds * 32;
  const int k4 = t * 4;

  float4 acc[BATCH];
  #pragma unroll
  for (int b = 0; b < BATCH; ++b) acc[b] = make_float4(0.f, 0.f, 0.f, 0.f);

  #pragma unroll 8
  for (int r = 0; r < 32; ++r) {
    const int row = r0 + r;
    const ushort4 tu = *(const ushort4*)&T1[(size_t)row * KCODES + k4];
    const float4 tv = make_float4(bf2f(tu.x), bf2f(tu.y), bf2f(tu.z), bf2f(tu.w));
    const float4 e0 = *(const float4*)&EST[row * BATCH + 0];
    const float4 e1 = *(const float4*)&EST[row * BATCH + 4];
    const float ev[8] = {e0.x, e0.y, e0.z, e0.w, e1.x, e1.y, e1.z, e1.w};
    #pragma unroll
    for (int b = 0; b < BATCH; ++b) {
      acc[b].x = fmaf(ev[b], tv.x, acc[b].x);
      acc[b].y = fmaf(ev[b], tv.y, acc[b].y);
      acc[b].z = fmaf(ev[b], tv.z, acc[b].z);
      acc[b].w = fmaf(ev[b], tv.w, acc[b].w);
    }
  }
  #pragma unroll
  for (int b = 0; b < BATCH; ++b) {
    __half* pp = &P[(size_t)ds * (BATCH * KCODES) + b * KCODES + k4];
    *(__half2*)(pp + 0) = __floats2half2_rn(acc[b].x, acc[b].y);
    *(__half2*)(pp + 2) = __floats2half2_rn(acc[b].z, acc[b].w);
  }
}

// ---- per-iter 1: chunked P all-reduce -> W = exp2(c2*S) (unnormalized) ----
// 256 blocks x 256 thr; block = (b2, k0..k0+31) chunk; thread = one slice.
__global__ __launch_bounds__(256) void k_wexp(float* __restrict__ ws,
                                              const int* __restrict__ nit_p,
                                              int it) {
  if (it >= *nit_p) return;
  const __half* P = (const __half*)(ws + P_OFF);
  float* W = ws + W_OFF;
  __shared__ float scr[128];
  const int t = threadIdx.x, lane = t & 63, wv = t >> 6;
  const int b2 = blockIdx.x >> 5;
  const int k0 = (blockIdx.x & 31) * 32;

  float4 raw[4];
  const float4* p4 =
      (const float4*)(P + (size_t)t * (BATCH * KCODES) + b2 * KCODES + k0);
  raw[0] = p4[0]; raw[1] = p4[1]; raw[2] = p4[2]; raw[3] = p4[3];
  const __half2* h2 = (const __half2*)raw;
  #pragma unroll
  for (int kk = 0; kk < 16; ++kk) {
    const float2 f2 = __half22float2(h2[kk]);
    const float s0 = wave_sum64(f2.x);
    const float s1 = wave_sum64(f2.y);
    if (lane == 63) {
      scr[wv * 32 + 2 * kk + 0] = s0;
      scr[wv * 32 + 2 * kk + 1] = s1;
    }
  }
  __syncthreads();
  if (t < 32) {
    const float s = scr[t] + scr[32 + t] + scr[64 + t] + scr[96 + t];
    W[b2 * KCODES + k0 + t] = exp2f(s * C2);
  }
}

// ---- per-iter 2: W.T1 est-GEMM -> normalize (LDS) -> next sims -> P ----
// 256 blocks x 512 thr; block = 32 T1 rows (16 dims), L2-hot via bid affinity.
__global__ __launch_bounds__(512) void k_fused(float* __restrict__ ws,
                                               const int* __restrict__ nit_p,
                                               int it) {
  if (it >= *nit_p) return;
  const ushort* T1 = (const ushort*)ws;
  const float*  Wg = ws + W_OFF;
  __half* P = (__half*)(ws + P_OFF);

  __shared__ float smem[BATCH * KCODES];   // 32 KB: W, then sims half-combine
  __shared__ float est_l[32 * BATCH];      // raw re/im -> normalized est

  const int t = threadIdx.x, lane = t & 63, wv = t >> 6;
  const int r0 = blockIdx.x * 32;

  #pragma unroll
  for (int j = 0; j < 4; ++j) {            // load full W into LDS
    const int idx = (j * 512 + t) * 4;
    *(float4*)&smem[idx] = *(const float4*)&Wg[idx];
  }
  __syncthreads();

  // phase 1: wave wv owns rows rw..rw+3; re/im = W . T1row
  const int rw = wv * 4;                   // local row base
  float acc[4][BATCH];
  #pragma unroll
  for (int r = 0; r < 4; ++r)
    #pragma unroll
    for (int b = 0; b < BATCH; ++b) acc[r][b] = 0.f;

  #pragma unroll
  for (int c = 0; c < 4; ++c) {
    const int kk = c * 256 + lane * 4;
    float4 wr[BATCH];
    #pragma unroll
    for (int b = 0; b < BATCH; ++b)
      wr[b] = *(const float4*)&smem[b * KCODES + kk];
    #pragma unroll
    for (int r = 0; r < 4; ++r) {
      const ushort4 tu = *(const ushort4*)&T1[(size_t)(r0 + rw + r) * KCODES + kk];
      const float4 tv = make_float4(bf2f(tu.x), bf2f(tu.y), bf2f(tu.z), bf2f(tu.w));
      #pragma unroll
      for (int b = 0; b < BATCH; ++b) {
        acc[r][b] = fmaf(wr[b].x, tv.x, acc[r][b]);
        acc[r][b] = fmaf(wr[b].y, tv.y, acc[r][b]);
        acc[r][b] = fmaf(wr[b].z, tv.z, acc[r][b]);
        acc[r][b] = fmaf(wr[b].w, tv.w, acc[r][b]);
      }
    }
  }
  #pragma unroll
  for (int r = 0; r < 4; ++r)
    #pragma unroll
    for (int b = 0; b < BATCH; ++b) {
      const float s = wave_sum64(acc[r][b]);
      if (lane == 63) est_l[(rw + r) * BATCH + b] = s;
    }
  __syncthreads();

  if (t < 128) {                           // normalize est in LDS
    const int dl = t >> 3, b = t & 7;
    const float re = est_l[(2 * dl + 0) * BATCH + b];
    const float im = est_l[(2 * dl + 1) * BATCH + b];
    const float n2 = fmaf(re, re, im * im);
    float ec, es;
    if (n2 > 0.f) {
      const float inv = rsqrtf(n2);
      ec = re * inv; es = im * inv;
    } else { ec = 1.f; es = 0.f; }         // atan2(0,0) = 0
    est_l[(2 * dl + 0) * BATCH + b] = ec;
    est_l[(2 * dl + 1) * BATCH + b] = es;
  }
  __syncthreads();

  // phase 2: next-iter sims partials for this slice (T1 rows L2-hot)
  const int half = t >> 8, tk = t & 255, k4 = tk * 4;
  const int rb = half * 16;
  float4 a[BATCH];
  #pragma unroll
  for (int b = 0; b < BATCH; ++b) a[b] = make_float4(0.f, 0.f, 0.f, 0.f);

  #pragma unroll
  for (int r = 0; r < 16; ++r) {
    const int lr = rb + r;
    const ushort4 tu = *(const ushort4*)&T1[(size_t)(r0 + lr) * KCODES + k4];
    const float4 tv = make_float4(bf2f(tu.x), bf2f(tu.y), bf2f(tu.z), bf2f(tu.w));
    const float4 e0 = *(const float4*)&est_l[lr * BATCH + 0];
    const float4 e1 = *(const float4*)&est_l[lr * BATCH + 4];
    const float ev[8] = {e0.x, e0.y, e0.z, e0.w, e1.x, e1.y, e1.z, e1.w};
    #pragma unroll
    for (int b = 0; b < BATCH; ++b) {
      a[b].x = fmaf(ev[b], tv.x, a[b].x);
      a[b].y = fmaf(ev[b], tv.y, a[b].y);
      a[b].z = fmaf(ev[b], tv.z, a[b].z);
      a[b].w = fmaf(ev[b], tv.w, a[b].w);
    }
  }
  if (half == 1) {
    #pragma unroll
    for (int b = 0; b < BATCH; ++b)
      *(float4*)&smem[(b * 256 + tk) * 4] = a[b];   // 16B lane stride: no conflicts
  }
  __syncthreads();
  if (half == 0) {
    #pragma unroll
    for (int b = 0; b < BATCH; ++b) {
      const float4 o = *(const float4*)&smem[(b * 256 + tk) * 4];
      __half* pp = &P[(size_t)blockIdx.x * (BATCH * KCODES) + b * KCODES + k4];
      *(__half2*)(pp + 0) = __floats2half2_rn(a[b].x + o.x, a[b].y + o.y);
      *(__half2*)(pp + 2) = __floats2half2_rn(a[b].z + o.z, a[b].w + o.w);
    }
  }
}

// ---- epilogue: out = (sum of 256 partials) / DIMS (chunked like k_wexp) ----
__global__ __launch_bounds__(256) void k_out(const float* __restrict__ ws,
                                             float* __restrict__ out) {
  const __half* P = (const __half*)(ws + P_OFF);
  __shared__ float scr[128];
  const int t = threadIdx.x, lane = t & 63, wv = t >> 6;
  const int b2 = blockIdx.x >> 5;
  const int k0 = (blockIdx.x & 31) * 32;

  float4 raw[4];
  const float4* p4 =
      (const float4*)(P + (size_t)t * (BATCH * KCODES) + b2 * KCODES + k0);
  raw[0] = p4[0]; raw[1] = p4[1]; raw[2] = p4[2]; raw[3] = p4[3];
  const __half2* h2 = (const __half2*)raw;
  #pragma unroll
  for (int kk = 0; kk < 16; ++kk) {
    const float2 f2 = __half22float2(h2[kk]);
    const float s0 = wave_sum64(f2.x);
    const float s1 = wave_sum64(f2.y);
    if (lane == 63) {
      scr[wv * 32 + 2 * kk + 0] = s0;
      scr[wv * 32 + 2 * kk + 1] = s1;
    }
  }
  __syncthreads();
  if (t < 32) {
    const float s = scr[t] + scr[32 + t] + scr[64 + t] + scr[96 + t];
    out[b2 * KCODES + k0 + t] = s * (1.0f / (float)DIMS);
  }
}

extern "C" void kernel_launch(void* const* d_in, const int* in_sizes, int n_in,
                              void* d_out, int out_size, void* d_ws, size_t ws_size,
                              hipStream_t stream) {
  const float* sup = (const float*)d_in[0];
  const float* cbk = (const float*)d_in[1];
  const int*   nit = (const int*)d_in[2];
  float* outp = (float*)d_out;
  float* ws   = (float*)d_ws;

  hipLaunchKernelGGL(k_trig,  dim3(1024), dim3(256), 0, stream, cbk, ws);
  hipLaunchKernelGGL(k_init,  dim3(128),  dim3(256), 0, stream, sup, ws);
  hipLaunchKernelGGL(k_sims0, dim3(256),  dim3(256), 0, stream, ws);

  for (int it = 0; it < NITER_MAX; ++it) {
    hipLaunchKernelGGL(k_wexp,  dim3(256), dim3(256), 0, stream, ws, nit, it);
    hipLaunchKernelGGL(k_fused, dim3(256), dim3(512), 0, stream, ws, nit, it);
  }
  hipLaunchKernelGGL(k_out, dim3(256), dim3(256), 0, stream, ws, outp);
}